// Round 6
// baseline (5141.179 us; speedup 1.0000x reference)
//
#include <hip/hip_runtime.h>
#include <hip/hip_bf16.h>
#include <math.h>

#define BT 2
#define SEQ 2048
#define DIM 1024
#define NH 16
#define HD 64
#define NTOK (BT*SEQ)          // 4096

typedef __attribute__((ext_vector_type(4))) float floatx4;
typedef __attribute__((ext_vector_type(8))) short shortx8;   // 8 bf16 = 4 VGPRs (MFMA frag)

__device__ __forceinline__ float bf2f(unsigned short u) {
    unsigned int x = ((unsigned int)u) << 16;
    return __builtin_bit_cast(float, x);
}
__device__ __forceinline__ unsigned short f2bf(float f) {
    unsigned int x = __builtin_bit_cast(unsigned int, f);
    unsigned int lsb = (x >> 16) & 1u;
    x += 0x7fffu + lsb;
    return (unsigned short)(x >> 16);
}
// dual-dtype input read: isbf=1 -> bf16, else fp32 (validated: inputs are fp32)
__device__ __forceinline__ float ldin_f(const void* p, size_t i, int isbf) {
    return isbf ? bf2f(((const unsigned short*)p)[i]) : ((const float*)p)[i];
}

// ---------------- input dtype detection (validated R1->R2) ----------------
__global__ void detect_kernel(const unsigned short* __restrict__ x, int* __restrict__ flag) {
    __shared__ int cnt;
    if (threadIdx.x == 0) cnt = 0;
    __syncthreads();
    unsigned short u = x[(size_t)threadIdx.x * 2];
    int e = (u >> 7) & 0xFF;
    if (e >= 100 && e <= 140) atomicAdd(&cnt, 1);
    __syncthreads();
    if (threadIdx.x == 0) *flag = (cnt >= 192) ? 1 : 0;
}

// ---------------- transpose (any float dtype -> bf16), dims multiples of 32 ----------
// (cross-validated R2 vs R4: gemm_bt on transposed weights == ngemm on native)
__global__ void transpose_any(const void* __restrict__ in,
                              unsigned short* __restrict__ out, int R, int C,
                              const int* __restrict__ flagp) {
    int isbf = *flagp;
    __shared__ unsigned short tile[32][33];
    int c0 = blockIdx.x * 32, r0 = blockIdx.y * 32;
    int tx = threadIdx.x, ty = threadIdx.y;
#pragma unroll
    for (int i = 0; i < 4; i++) {
        size_t idx = (size_t)(r0 + ty + i * 8) * C + c0 + tx;
        tile[ty + i * 8][tx] = isbf ? ((const unsigned short*)in)[idx]
                                    : f2bf(((const float*)in)[idx]);
    }
    __syncthreads();
#pragma unroll
    for (int i = 0; i < 4; i++)
        out[(size_t)(c0 + ty + i * 8) * R + r0 + tx] = tile[tx][ty + i * 8];
}

// ---------------- Householder Q (64x64 fp32) ----------------
__global__ void householder_kernel(const void* __restrict__ vs,
                                   float* __restrict__ Qg,
                                   const int* __restrict__ flagp) {
    int isbf = *flagp;
    __shared__ float Qm[64][65];
    __shared__ float vsh[64];
    int j = threadIdx.x;
    for (int i = 0; i < 64; i++) Qm[i][j] = (i == j) ? 1.f : 0.f;
    __syncthreads();
    for (int r = 0; r < 32; r++) {
        vsh[j] = ldin_f(vs, r * 64 + j, isbf);
        __syncthreads();
        float vn = 1e-8f;
        for (int i = 0; i < 64; i++) vn += vsh[i] * vsh[i];
        float t = 0.f;
        for (int i = 0; i < 64; i++) t += vsh[i] * Qm[i][j];
        float c = (2.f / vn) * t;
        for (int i = 0; i < 64; i++) Qm[i][j] -= c * vsh[i];
        __syncthreads();
    }
    for (int i = 0; i < 64; i++) Qg[i * 64 + j] = Qm[i][j];
}

// ---------------- rmsnorm over D=1024, LDS tree reduction ----------------
__global__ __launch_bounds__(256) void rmsnorm2(const void* __restrict__ x,
                                                unsigned short* __restrict__ h,
                                                const int* __restrict__ flagp) {
    int isbf = flagp ? *flagp : 1;
    __shared__ float red[256];
    int row = blockIdx.x, t = threadIdx.x;
    size_t base = (size_t)row * DIM;
    float v[4];
    float ss = 0.f;
#pragma unroll
    for (int i = 0; i < 4; i++) {
        v[i] = ldin_f(x, base + t + 256 * i, isbf);
        ss += v[i] * v[i];
    }
    red[t] = ss;
    __syncthreads();
    for (int s = 128; s > 0; s >>= 1) {
        if (t < s) red[t] += red[t + s];
        __syncthreads();
    }
    float rs = rsqrtf(red[0] * (1.f / 1024.f) + 1e-6f);
#pragma unroll
    for (int i = 0; i < 4; i++) h[base + t + 256 * i] = f2bf(v[i] * rs);
}

// ---------------- MFMA GEMM: C[M,N] = A[M,K] * Bt[N,K]^T (+bias +resid) --------------
// c_f32: store C as fp32 (for d_out, whose dtype follows the fp32 reference output)
#define GBM 128
#define GBN 128
#define GBK 32
#define ASTR 40

__global__ __launch_bounds__(256) void gemm_bt(const unsigned short* __restrict__ A,
                                               const unsigned short* __restrict__ Bt,
                                               void* __restrict__ C,
                                               const void* __restrict__ bias,
                                               const unsigned short* __restrict__ resid,
                                               const int* __restrict__ flagp,
                                               int M, int N, int K, int c_f32) {
    __shared__ unsigned short As[GBM][ASTR];
    __shared__ unsigned short Bs[GBN][ASTR];
    int bisbf = (bias && flagp) ? *flagp : 1;
    int nbn = N / GBN;
    int m0 = (blockIdx.x / nbn) * GBM;
    int n0 = (blockIdx.x % nbn) * GBN;
    int t = threadIdx.x;
    int lane = t & 63;
    int w = t >> 6;
    int wr = (w >> 1) * 64;
    int wc = (w & 1) * 64;
    int lr = lane & 15;
    int kg = lane >> 4;

    floatx4 acc[4][4];
#pragma unroll
    for (int i = 0; i < 4; i++)
#pragma unroll
        for (int j = 0; j < 4; j++) acc[i][j] = (floatx4){0.f, 0.f, 0.f, 0.f};

    int srow = t >> 1;
    int skseg = (t & 1) * 16;
    const unsigned short* Aptr = A + (size_t)(m0 + srow) * K + skseg;
    const unsigned short* Bptr = Bt + (size_t)(n0 + srow) * K + skseg;

    for (int k0 = 0; k0 < K; k0 += GBK) {
        shortx8 a0 = *(const shortx8*)(Aptr + k0);
        shortx8 a1 = *(const shortx8*)(Aptr + k0 + 8);
        shortx8 b0 = *(const shortx8*)(Bptr + k0);
        shortx8 b1 = *(const shortx8*)(Bptr + k0 + 8);
        __syncthreads();
        *(shortx8*)&As[srow][skseg] = a0;
        *(shortx8*)&As[srow][skseg + 8] = a1;
        *(shortx8*)&Bs[srow][skseg] = b0;
        *(shortx8*)&Bs[srow][skseg + 8] = b1;
        __syncthreads();
        shortx8 af[4], bfv[4];
#pragma unroll
        for (int i = 0; i < 4; i++) af[i] = *(const shortx8*)&As[wr + i * 16 + lr][kg * 8];
#pragma unroll
        for (int j = 0; j < 4; j++) bfv[j] = *(const shortx8*)&Bs[wc + j * 16 + lr][kg * 8];
#pragma unroll
        for (int i = 0; i < 4; i++)
#pragma unroll
            for (int j = 0; j < 4; j++)
                acc[i][j] = __builtin_amdgcn_mfma_f32_16x16x32_bf16(af[i], bfv[j], acc[i][j], 0, 0, 0);
    }
#pragma unroll
    for (int i = 0; i < 4; i++) {
#pragma unroll
        for (int j = 0; j < 4; j++) {
            int col = n0 + wc + j * 16 + lr;
            int rbase = m0 + wr + i * 16 + kg * 4;
            float bv = bias ? ldin_f(bias, col, bisbf) : 0.f;
#pragma unroll
            for (int r = 0; r < 4; r++) {
                float val = acc[i][j][r] + bv;
                size_t oidx = (size_t)(rbase + r) * N + col;
                if (resid) val += bf2f(resid[oidx]);
                if (c_f32) ((float*)C)[oidx] = val;
                else       ((unsigned short*)C)[oidx] = f2bf(val);
            }
        }
    }
}

// ---------------- Householder^-1 + RoPE + Householder (R5-validated form) ------------
// One 64-thread block per (token, head); outputs bf16 [B,H,S,HD].
__global__ __launch_bounds__(64) void qk_rope2(const unsigned short* __restrict__ qkv,
                                               const float* __restrict__ Qg,
                                               unsigned short* __restrict__ q_r,
                                               unsigned short* __restrict__ k_r,
                                               unsigned short* __restrict__ v_r) {
    int blk = blockIdx.x;            // = ts*16 + h
    int h = blk & 15;
    int ts = blk >> 4;               // b*SEQ + s
    int s = ts & 2047;
    int b = ts >> 11;
    int d = threadIdx.x;             // 0..63
    __shared__ float qs[64], ks[64], q1s[64], k1s[64];
    const unsigned short* base = qkv + (size_t)ts * 3072 + h * 64;
    qs[d] = bf2f(base[d]);
    ks[d] = bf2f(base[1024 + d]);
    unsigned short vv = base[2048 + d];
    __syncthreads();
    // q1 = q @ Q^T : q1[d] = sum_j Q[d][j] * q[j]
    const float* Qrow = Qg + d * 64;
    float q1 = 0.f, k1 = 0.f;
    for (int j = 0; j < 64; j++) { q1 += Qrow[j] * qs[j]; k1 += Qrow[j] * ks[j]; }
    q1s[d] = q1; k1s[d] = k1;
    __syncthreads();
    // rope: out[d] = in[d]*cos + rot[d]*sin, rot = [-x2 | x1], angle in radians
    int fi = d & 31;
    float invf = powf(10000.f, -(float)fi / 32.f);
    float ang = (float)s * invf;
    float cv = cosf(ang), sv = sinf(ang);
    float rq = (d < 32) ? -q1s[d + 32] : q1s[d - 32];
    float rk = (d < 32) ? -k1s[d + 32] : k1s[d - 32];
    float q2 = q1 * cv + rq * sv;
    float k2 = k1 * cv + rk * sv;
    __syncthreads();
    q1s[d] = q2; k1s[d] = k2;
    __syncthreads();
    // q3 = q2 @ Q : q3[d] = sum_j Q[j][d] * q2[j]
    float q3 = 0.f, k3 = 0.f;
    for (int j = 0; j < 64; j++) {
        float Qjd = Qg[j * 64 + d];
        q3 += Qjd * q1s[j];
        k3 += Qjd * k1s[j];
    }
    size_t bh_off = ((size_t)(b * NH + h) * SEQ + s) * HD;
    q_r[bh_off + d] = f2bf(q3);
    k_r[bh_off + d] = f2bf(k3);
    v_r[bh_off + d] = vv;
}

// ---------------- block-causal attention (R5-validated form): 1 thread = 1 q-row -----
__global__ __launch_bounds__(64) void attn2(const unsigned short* __restrict__ q_r,
                                            const unsigned short* __restrict__ k_r,
                                            const unsigned short* __restrict__ v_r,
                                            unsigned short* __restrict__ attn) {
    int gid = blockIdx.x * 64 + threadIdx.x;   // over B*H*S = 65536 q-rows
    int bh = gid >> 11;
    int s = gid & 2047;
    int b = bh >> 4, h = bh & 15;
    size_t bh_off = (size_t)bh * SEQ * HD;
    const unsigned short* qp = q_r + bh_off + (size_t)s * HD;
    float q[64];
#pragma unroll
    for (int u = 0; u < 8; u++) {
        shortx8 qw = *(const shortx8*)(qp + u * 8);
#pragma unroll
        for (int e = 0; e < 8; e++) q[u * 8 + e] = bf2f((unsigned short)qw[e]) * 0.125f;
    }
    float o[64];
#pragma unroll
    for (int d = 0; d < 64; d++) o[d] = 0.f;
    float mx = -1e30f, l = 0.f;
    int nk = ((s >> 7) + 1) << 7;              // block-causal: keys < (qblk+1)*128
#pragma unroll 1
    for (int j = 0; j < nk; j++) {
        const unsigned short* kp = k_r + bh_off + (size_t)j * HD;
        float sc = 0.f;
#pragma unroll
        for (int u = 0; u < 8; u++) {
            shortx8 kw = *(const shortx8*)(kp + u * 8);
#pragma unroll
            for (int e = 0; e < 8; e++) sc += q[u * 8 + e] * bf2f((unsigned short)kw[e]);
        }
        float nm = fmaxf(mx, sc);
        float alpha = __expf(mx - nm);
        float p = __expf(sc - nm);
        l = l * alpha + p;
        const unsigned short* vp = v_r + bh_off + (size_t)j * HD;
#pragma unroll
        for (int u = 0; u < 8; u++) {
            shortx8 vw = *(const shortx8*)(vp + u * 8);
#pragma unroll
            for (int e = 0; e < 8; e++) o[u * 8 + e] = o[u * 8 + e] * alpha + p * bf2f((unsigned short)vw[e]);
        }
        mx = nm;
    }
    float inv_l = 1.f / l;
    int tok = b * SEQ + s;
    unsigned short* op = attn + (size_t)tok * DIM + h * 64;
#pragma unroll
    for (int d = 0; d < 64; d++) op[d] = f2bf(o[d] * inv_l);
}

// ---------------- gated residual combine: x1 = x + ao*sigmoid(gl + bg) ----------------
__global__ void combine_gate(const void* __restrict__ x,
                             const unsigned short* __restrict__ ao,
                             const unsigned short* __restrict__ gl,
                             const void* __restrict__ bg,
                             unsigned short* __restrict__ x1,
                             const int* __restrict__ flagp) {
    int isbf = *flagp;
    size_t idx = (size_t)blockIdx.x * 256 + threadIdx.x;
    float a = bf2f(ao[idx]);
    float z = bf2f(gl[idx]) + ldin_f(bg, idx & 1023, isbf);
    float sg = 1.f / (1.f + __expf(-z));
    x1[idx] = f2bf(ldin_f(x, idx, isbf) + a * sg);
}

// ---------------- GLU with exact GELU ----------------
__global__ void glu_kernel(const unsigned short* __restrict__ gv,
                           unsigned short* __restrict__ act) {
    size_t idx = (size_t)blockIdx.x * 256 + threadIdx.x;     // over 4096*4096
    size_t m = idx >> 12, n = idx & 4095;
    float g = bf2f(gv[m * 8192 + n]);
    float val = bf2f(gv[m * 8192 + 4096 + n]);
    float ge = 0.5f * g * (1.f + erff(g * 0.70710678118f));
    act[idx] = f2bf(val * ge);
}

extern "C" void kernel_launch(void* const* d_in, const int* in_sizes, int n_in,
                              void* d_out, int out_size, void* d_ws, size_t ws_size,
                              hipStream_t stream) {
    const unsigned short* x        = (const unsigned short*)d_in[0];
    // d_in[1] mask (block-causal, derived analytically) and d_in[2] grid_size unused
    const void* vs       = d_in[3];
    const void* w_qkv    = d_in[4];
    const void* w_out    = d_in[5];
    const void* w_gate   = d_in[6];
    const void* b_gate   = d_in[7];
    const void* w_mlp_g  = d_in[8];
    const void* b_mlp_g  = d_in[9];
    const void* w_mlp_o  = d_in[10];
    const void* b_mlp_o  = d_in[11];
    float* out = (float*)d_out;    // reference output dtype is float32
    char* ws = (char*)d_ws;

    if (n_in < 12) return;
    if (in_sizes[0] != 4194304 || in_sizes[3] != 2048 || in_sizes[4] != 3145728 ||
        in_sizes[8] != 8388608 || in_sizes[10] != 4194304 || in_sizes[7] != 1024) return;

    // ws layout (161,513,472 bytes total; known-safe: R2 ran with 178 MB)
    const size_t o_T   = 0;            // transposed weights, 35,651,584
    const size_t o_Qg  = 35651584;     // Qg 16 KiB + flag (32 KiB reserved)
    const size_t o_h   = 35684352;     // 8,388,608
    const size_t o_B   = 44072960;     // 25,165,824: qkv | attnb, ao, gl
    const size_t o_C   = 69238784;     // 25,165,824: q_rb,k_rb,v_rb | x1, act
    const size_t o_gv  = 94404608;     // 67,108,864
    const size_t total = 161513472;
    if (ws_size < total) return;

    unsigned short* wqkvT  = (unsigned short*)(ws + o_T);             // [3072,1024]
    unsigned short* woutT  = (unsigned short*)(ws + o_T + 6291456);   // [1024,1024]
    unsigned short* wgateT = (unsigned short*)(ws + o_T + 8388608);   // [1024,1024]
    unsigned short* wmgT   = (unsigned short*)(ws + o_T + 10485760);  // [8192,1024]
    unsigned short* wmoT   = (unsigned short*)(ws + o_T + 27262976);  // [1024,4096]
    float*          Qg     = (float*)(ws + o_Qg);
    int*            flagp  = (int*)(ws + o_Qg + 16384);
    unsigned short* h      = (unsigned short*)(ws + o_h);
    unsigned short* qkv    = (unsigned short*)(ws + o_B);
    unsigned short* attnb  = (unsigned short*)(ws + o_B);             // after qkv dead
    unsigned short* ao     = (unsigned short*)(ws + o_B + 8388608);
    unsigned short* gl     = (unsigned short*)(ws + o_B + 16777216);
    unsigned short* q_rb   = (unsigned short*)(ws + o_C);
    unsigned short* k_rb   = (unsigned short*)(ws + o_C + 8388608);
    unsigned short* v_rb   = (unsigned short*)(ws + o_C + 16777216);
    unsigned short* x1     = (unsigned short*)(ws + o_C);             // after attn done
    unsigned short* act    = (unsigned short*)(ws + o_C + 8388608);   // after attn done
    unsigned short* gv     = (unsigned short*)(ws + o_gv);

    detect_kernel<<<1, 256, 0, stream>>>(x, flagp);
    householder_kernel<<<1, 64, 0, stream>>>(vs, Qg, flagp);

    dim3 tb(32, 8);
    transpose_any<<<dim3(3072 / 32, 1024 / 32), tb, 0, stream>>>(w_qkv,   wqkvT, 1024, 3072, flagp);
    transpose_any<<<dim3(1024 / 32, 1024 / 32), tb, 0, stream>>>(w_out,   woutT, 1024, 1024, flagp);
    transpose_any<<<dim3(1024 / 32, 1024 / 32), tb, 0, stream>>>(w_gate,  wgateT, 1024, 1024, flagp);
    transpose_any<<<dim3(8192 / 32, 1024 / 32), tb, 0, stream>>>(w_mlp_g, wmgT, 1024, 8192, flagp);
    transpose_any<<<dim3(1024 / 32, 4096 / 32), tb, 0, stream>>>(w_mlp_o, wmoT, 4096, 1024, flagp);

    rmsnorm2<<<NTOK, 256, 0, stream>>>(x, h, flagp);
    gemm_bt<<<32 * 24, 256, 0, stream>>>(h, wqkvT, qkv, nullptr, nullptr, flagp, NTOK, 3072, 1024, 0);
    qk_rope2<<<NTOK * NH, 64, 0, stream>>>(qkv, Qg, q_rb, k_rb, v_rb);
    attn2<<<BT * NH * SEQ / 64, 64, 0, stream>>>(q_rb, k_rb, v_rb, attnb);
    gemm_bt<<<32 * 8, 256, 0, stream>>>(attnb, woutT, ao, nullptr, nullptr, flagp, NTOK, 1024, 1024, 0);
    gemm_bt<<<32 * 8, 256, 0, stream>>>(ao, wgateT, gl, nullptr, nullptr, flagp, NTOK, 1024, 1024, 0);
    combine_gate<<<NTOK * DIM / 256, 256, 0, stream>>>(x, ao, gl, b_gate, x1, flagp);
    rmsnorm2<<<NTOK, 256, 0, stream>>>(x1, h, nullptr);
    gemm_bt<<<32 * 64, 256, 0, stream>>>(h, wmgT, gv, b_mlp_g, nullptr, flagp, NTOK, 8192, 1024, 0);
    glu_kernel<<<NTOK * 4096 / 256, 256, 0, stream>>>(gv, act);
    gemm_bt<<<32 * 8, 256, 0, stream>>>(act, wmoT, (void*)out, b_mlp_o, x1, flagp, NTOK, 1024, 4096, 1);
}

// Round 7
// 1129.917 us; speedup vs baseline: 4.5501x; 4.5501x over previous
//
#include <hip/hip_runtime.h>
#include <hip/hip_bf16.h>
#include <math.h>

#define BT 2
#define SEQ 2048
#define DIM 1024
#define NH 16
#define HD 64
#define NTOK (BT*SEQ)          // 4096

typedef __attribute__((ext_vector_type(4))) float floatx4;
typedef __attribute__((ext_vector_type(8))) short shortx8;   // 8 bf16 = 4 VGPRs (MFMA frag)
typedef __attribute__((ext_vector_type(4))) short shortx4;

__device__ __forceinline__ float bf2f(unsigned short u) {
    unsigned int x = ((unsigned int)u) << 16;
    return __builtin_bit_cast(float, x);
}
__device__ __forceinline__ unsigned short f2bf(float f) {
    unsigned int x = __builtin_bit_cast(unsigned int, f);
    unsigned int lsb = (x >> 16) & 1u;
    x += 0x7fffu + lsb;
    return (unsigned short)(x >> 16);
}
// dual-dtype input read: isbf=1 -> bf16, else fp32 (validated: inputs are fp32)
__device__ __forceinline__ float ldin_f(const void* p, size_t i, int isbf) {
    return isbf ? bf2f(((const unsigned short*)p)[i]) : ((const float*)p)[i];
}

// ---------------- input dtype detection (validated R1->R2) ----------------
__global__ void detect_kernel(const unsigned short* __restrict__ x, int* __restrict__ flag) {
    __shared__ int cnt;
    if (threadIdx.x == 0) cnt = 0;
    __syncthreads();
    unsigned short u = x[(size_t)threadIdx.x * 2];
    int e = (u >> 7) & 0xFF;
    if (e >= 100 && e <= 140) atomicAdd(&cnt, 1);
    __syncthreads();
    if (threadIdx.x == 0) *flag = (cnt >= 192) ? 1 : 0;
}

// ---------------- transpose (any float dtype -> bf16) ----------------
__global__ void transpose_any(const void* __restrict__ in,
                              unsigned short* __restrict__ out, int R, int C,
                              const int* __restrict__ flagp) {
    int isbf = *flagp;
    __shared__ unsigned short tile[32][33];
    int c0 = blockIdx.x * 32, r0 = blockIdx.y * 32;
    int tx = threadIdx.x, ty = threadIdx.y;
#pragma unroll
    for (int i = 0; i < 4; i++) {
        size_t idx = (size_t)(r0 + ty + i * 8) * C + c0 + tx;
        tile[ty + i * 8][tx] = isbf ? ((const unsigned short*)in)[idx]
                                    : f2bf(((const float*)in)[idx]);
    }
    __syncthreads();
#pragma unroll
    for (int i = 0; i < 4; i++)
        out[(size_t)(c0 + ty + i * 8) * R + r0 + tx] = tile[tx][ty + i * 8];
}

// ---------------- Householder Q (64x64 fp32) ----------------
__global__ void householder_kernel(const void* __restrict__ vs,
                                   float* __restrict__ Qg,
                                   const int* __restrict__ flagp) {
    int isbf = *flagp;
    __shared__ float Qm[64][65];
    __shared__ float vsh[64];
    int j = threadIdx.x;
    for (int i = 0; i < 64; i++) Qm[i][j] = (i == j) ? 1.f : 0.f;
    __syncthreads();
    for (int r = 0; r < 32; r++) {
        vsh[j] = ldin_f(vs, r * 64 + j, isbf);
        __syncthreads();
        float vn = 1e-8f;
        for (int i = 0; i < 64; i++) vn += vsh[i] * vsh[i];
        float t = 0.f;
        for (int i = 0; i < 64; i++) t += vsh[i] * Qm[i][j];
        float c = (2.f / vn) * t;
        for (int i = 0; i < 64; i++) Qm[i][j] -= c * vsh[i];
        __syncthreads();
    }
    for (int i = 0; i < 64; i++) Qg[i * 64 + j] = Qm[i][j];
}

// ---------------- rmsnorm over D=1024, LDS tree reduction ----------------
__global__ __launch_bounds__(256) void rmsnorm2(const void* __restrict__ x,
                                                unsigned short* __restrict__ h,
                                                const int* __restrict__ flagp) {
    int isbf = flagp ? *flagp : 1;
    __shared__ float red[256];
    int row = blockIdx.x, t = threadIdx.x;
    size_t base = (size_t)row * DIM;
    float v[4];
    float ss = 0.f;
#pragma unroll
    for (int i = 0; i < 4; i++) {
        v[i] = ldin_f(x, base + t + 256 * i, isbf);
        ss += v[i] * v[i];
    }
    red[t] = ss;
    __syncthreads();
    for (int s = 128; s > 0; s >>= 1) {
        if (t < s) red[t] += red[t + s];
        __syncthreads();
    }
    float rs = rsqrtf(red[0] * (1.f / 1024.f) + 1e-6f);
#pragma unroll
    for (int i = 0; i < 4; i++) h[base + t + 256 * i] = f2bf(v[i] * rs);
}

// ---------------- MFMA GEMM: C[M,N] = A[M,K] * Bt[N,K]^T (+bias +resid) --------------
#define GBM 128
#define GBN 128
#define GBK 32
#define ASTR 40

__global__ __launch_bounds__(256) void gemm_bt(const unsigned short* __restrict__ A,
                                               const unsigned short* __restrict__ Bt,
                                               void* __restrict__ C,
                                               const void* __restrict__ bias,
                                               const unsigned short* __restrict__ resid,
                                               const int* __restrict__ flagp,
                                               int M, int N, int K, int c_f32) {
    __shared__ unsigned short As[GBM][ASTR];
    __shared__ unsigned short Bs[GBN][ASTR];
    int bisbf = (bias && flagp) ? *flagp : 1;
    int nbn = N / GBN;
    int m0 = (blockIdx.x / nbn) * GBM;
    int n0 = (blockIdx.x % nbn) * GBN;
    int t = threadIdx.x;
    int lane = t & 63;
    int w = t >> 6;
    int wr = (w >> 1) * 64;
    int wc = (w & 1) * 64;
    int lr = lane & 15;
    int kg = lane >> 4;

    floatx4 acc[4][4];
#pragma unroll
    for (int i = 0; i < 4; i++)
#pragma unroll
        for (int j = 0; j < 4; j++) acc[i][j] = (floatx4){0.f, 0.f, 0.f, 0.f};

    int srow = t >> 1;
    int skseg = (t & 1) * 16;
    const unsigned short* Aptr = A + (size_t)(m0 + srow) * K + skseg;
    const unsigned short* Bptr = Bt + (size_t)(n0 + srow) * K + skseg;

    for (int k0 = 0; k0 < K; k0 += GBK) {
        shortx8 a0 = *(const shortx8*)(Aptr + k0);
        shortx8 a1 = *(const shortx8*)(Aptr + k0 + 8);
        shortx8 b0 = *(const shortx8*)(Bptr + k0);
        shortx8 b1 = *(const shortx8*)(Bptr + k0 + 8);
        __syncthreads();
        *(shortx8*)&As[srow][skseg] = a0;
        *(shortx8*)&As[srow][skseg + 8] = a1;
        *(shortx8*)&Bs[srow][skseg] = b0;
        *(shortx8*)&Bs[srow][skseg + 8] = b1;
        __syncthreads();
        shortx8 af[4], bfv[4];
#pragma unroll
        for (int i = 0; i < 4; i++) af[i] = *(const shortx8*)&As[wr + i * 16 + lr][kg * 8];
#pragma unroll
        for (int j = 0; j < 4; j++) bfv[j] = *(const shortx8*)&Bs[wc + j * 16 + lr][kg * 8];
#pragma unroll
        for (int i = 0; i < 4; i++)
#pragma unroll
            for (int j = 0; j < 4; j++)
                acc[i][j] = __builtin_amdgcn_mfma_f32_16x16x32_bf16(af[i], bfv[j], acc[i][j], 0, 0, 0);
    }
#pragma unroll
    for (int i = 0; i < 4; i++) {
#pragma unroll
        for (int j = 0; j < 4; j++) {
            int col = n0 + wc + j * 16 + lr;
            int rbase = m0 + wr + i * 16 + kg * 4;
            float bv = bias ? ldin_f(bias, col, bisbf) : 0.f;
#pragma unroll
            for (int r = 0; r < 4; r++) {
                float val = acc[i][j][r] + bv;
                size_t oidx = (size_t)(rbase + r) * N + col;
                if (resid) val += bf2f(resid[oidx]);
                if (c_f32) ((float*)C)[oidx] = val;
                else       ((unsigned short*)C)[oidx] = f2bf(val);
            }
        }
    }
}

// ---------------- Householder^-1 + RoPE + Householder (R6-validated) ------------
__global__ __launch_bounds__(64) void qk_rope2(const unsigned short* __restrict__ qkv,
                                               const float* __restrict__ Qg,
                                               unsigned short* __restrict__ q_r,
                                               unsigned short* __restrict__ k_r,
                                               unsigned short* __restrict__ v_r) {
    int blk = blockIdx.x;            // = ts*16 + h
    int h = blk & 15;
    int ts = blk >> 4;               // b*SEQ + s
    int s = ts & 2047;
    int b = ts >> 11;
    int d = threadIdx.x;             // 0..63
    __shared__ float qs[64], ks[64], q1s[64], k1s[64];
    const unsigned short* base = qkv + (size_t)ts * 3072 + h * 64;
    qs[d] = bf2f(base[d]);
    ks[d] = bf2f(base[1024 + d]);
    unsigned short vv = base[2048 + d];
    __syncthreads();
    const float* Qrow = Qg + d * 64;
    float q1 = 0.f, k1 = 0.f;
    for (int j = 0; j < 64; j++) { q1 += Qrow[j] * qs[j]; k1 += Qrow[j] * ks[j]; }
    q1s[d] = q1; k1s[d] = k1;
    __syncthreads();
    int fi = d & 31;
    float invf = powf(10000.f, -(float)fi / 32.f);
    float ang = (float)s * invf;
    float cv = cosf(ang), sv = sinf(ang);
    float rq = (d < 32) ? -q1s[d + 32] : q1s[d - 32];
    float rk = (d < 32) ? -k1s[d + 32] : k1s[d - 32];
    float q2 = q1 * cv + rq * sv;
    float k2 = k1 * cv + rk * sv;
    __syncthreads();
    q1s[d] = q2; k1s[d] = k2;
    __syncthreads();
    float q3 = 0.f, k3 = 0.f;
    for (int j = 0; j < 64; j++) {
        float Qjd = Qg[j * 64 + d];
        q3 += Qjd * q1s[j];
        k3 += Qjd * k1s[j];
    }
    size_t bh_off = ((size_t)(b * NH + h) * SEQ + s) * HD;
    q_r[bh_off + d] = f2bf(q3);
    k_r[bh_off + d] = f2bf(k3);
    v_r[bh_off + d] = vv;
}

// ---------------- MFMA flash attention (block-causal) -------------------------------
// 1 block = 512 threads = 8 waves, per (bh, 128-row q-block). Wave owns 16 q-rows.
// Fragment layouts (validated by gemm_bt in this session + m89/m120):
//   A: [m=lane&15][k=quad*8+j]   B: [k=quad*8+j][n=lane&15]   C/D: [row=quad*4+r][col=lane&15]
__global__ __launch_bounds__(512) void attn_mfma(const unsigned short* __restrict__ q_r,
                                                 const unsigned short* __restrict__ k_r,
                                                 const unsigned short* __restrict__ v_r,
                                                 unsigned short* __restrict__ attn) {
    __shared__ unsigned short Ks[32][72];        // K-tile [key][dim], stride 144B (16B-mult)
    __shared__ unsigned short Vt[64][40];        // V^T tile [dim][key], stride 80B
    __shared__ unsigned short Ps[8][16][40];     // per-wave P round-trip [row][key]
    int bid = blockIdx.x;
    int qblk = 15 - (bid & 15);                  // big q-blocks first
    int bh = bid >> 4;
    int b = bh >> 4, h = bh & 15;
    size_t bh_off = (size_t)bh * SEQ * HD;
    int tid = threadIdx.x;
    int wv = tid >> 6, lane = tid & 63;
    int l16 = lane & 15, quad = lane >> 4;
    int q0 = qblk * 128 + wv * 16;

    // Q A-frags for this wave's 16 rows (dims 0..31 and 32..63)
    const unsigned short* qrow = q_r + bh_off + (size_t)(q0 + l16) * HD + quad * 8;
    shortx8 aq0 = *(const shortx8*)(qrow);
    shortx8 aq1 = *(const shortx8*)(qrow + 32);

    floatx4 o[4];
#pragma unroll
    for (int nt = 0; nt < 4; nt++) o[nt] = (floatx4){0.f, 0.f, 0.f, 0.f};
    float m4[4] = {-1e30f, -1e30f, -1e30f, -1e30f};
    float l4[4] = {0.f, 0.f, 0.f, 0.f};

    int nk = (qblk + 1) * 128;
    int srow = tid >> 4;              // 0..31 (staging)
    int scol = (tid & 15) * 4;        // 0..60
    const unsigned short* kbase = k_r + bh_off + (size_t)srow * HD + scol;
    const unsigned short* vbase = v_r + bh_off + (size_t)srow * HD + scol;

    for (int k0 = 0; k0 < nk; k0 += 32) {
        __syncthreads();              // prev iteration's LDS reads done
        shortx4 kv4 = *(const shortx4*)(kbase + (size_t)k0 * HD);
        shortx4 vv4 = *(const shortx4*)(vbase + (size_t)k0 * HD);
        *(shortx4*)&Ks[srow][scol] = kv4;
        Vt[scol + 0][srow] = vv4[0];
        Vt[scol + 1][srow] = vv4[1];
        Vt[scol + 2][srow] = vv4[2];
        Vt[scol + 3][srow] = vv4[3];
        __syncthreads();              // staging visible

        // S = Q K^T for 32 keys -> two 16x16 C-tiles
        floatx4 sc[2];
#pragma unroll
        for (int t = 0; t < 2; t++) {
            shortx8 bk0 = *(const shortx8*)&Ks[t * 16 + l16][quad * 8];
            shortx8 bk1 = *(const shortx8*)&Ks[t * 16 + l16][32 + quad * 8];
            floatx4 z = (floatx4){0.f, 0.f, 0.f, 0.f};
            z = __builtin_amdgcn_mfma_f32_16x16x32_bf16(aq0, bk0, z, 0, 0, 0);
            z = __builtin_amdgcn_mfma_f32_16x16x32_bf16(aq1, bk1, z, 0, 0, 0);
            sc[t] = z;
        }
        // online softmax (row = quad*4+r; 16 keys of a row live in the quad's 16 lanes)
#pragma unroll
        for (int r = 0; r < 4; r++) {
            float s0 = sc[0][r] * 0.125f;
            float s1 = sc[1][r] * 0.125f;
            float mt = fmaxf(s0, s1);
#pragma unroll
            for (int msk = 1; msk < 16; msk <<= 1) mt = fmaxf(mt, __shfl_xor(mt, msk, 64));
            float nmr = fmaxf(m4[r], mt);
            float al = __expf(m4[r] - nmr);
            m4[r] = nmr;
            float p0 = __expf(s0 - nmr);
            float p1 = __expf(s1 - nmr);
            float ps = p0 + p1;
#pragma unroll
            for (int msk = 1; msk < 16; msk <<= 1) ps += __shfl_xor(ps, msk, 64);
            l4[r] = l4[r] * al + ps;
#pragma unroll
            for (int nt = 0; nt < 4; nt++) o[nt][r] *= al;
            Ps[wv][quad * 4 + r][l16] = f2bf(p0);
            Ps[wv][quad * 4 + r][16 + l16] = f2bf(p1);
        }
        __syncthreads();              // P visible (uniform; also orders wave-local LDS)

        // O += P V  (reduction over 32 keys)
        shortx8 ap = *(const shortx8*)&Ps[wv][l16][quad * 8];
#pragma unroll
        for (int nt = 0; nt < 4; nt++) {
            shortx8 bv = *(const shortx8*)&Vt[nt * 16 + l16][quad * 8];
            o[nt] = __builtin_amdgcn_mfma_f32_16x16x32_bf16(ap, bv, o[nt], 0, 0, 0);
        }
    }
    // epilogue: normalize rows, write [B,S,H*64]
#pragma unroll
    for (int r = 0; r < 4; r++) {
        float inv_l = 1.f / l4[r];
        int s = q0 + quad * 4 + r;
        unsigned short* op = attn + ((size_t)(b * SEQ + s)) * DIM + h * 64;
#pragma unroll
        for (int nt = 0; nt < 4; nt++) op[nt * 16 + l16] = f2bf(o[nt][r] * inv_l);
    }
}

// ---------------- gated residual combine: x1 = x + ao*sigmoid(gl + bg) ----------------
__global__ void combine_gate(const void* __restrict__ x,
                             const unsigned short* __restrict__ ao,
                             const unsigned short* __restrict__ gl,
                             const void* __restrict__ bg,
                             unsigned short* __restrict__ x1,
                             const int* __restrict__ flagp) {
    int isbf = *flagp;
    size_t idx = (size_t)blockIdx.x * 256 + threadIdx.x;
    float a = bf2f(ao[idx]);
    float z = bf2f(gl[idx]) + ldin_f(bg, idx & 1023, isbf);
    float sg = 1.f / (1.f + __expf(-z));
    x1[idx] = f2bf(ldin_f(x, idx, isbf) + a * sg);
}

// ---------------- GLU with exact GELU ----------------
__global__ void glu_kernel(const unsigned short* __restrict__ gv,
                           unsigned short* __restrict__ act) {
    size_t idx = (size_t)blockIdx.x * 256 + threadIdx.x;     // over 4096*4096
    size_t m = idx >> 12, n = idx & 4095;
    float g = bf2f(gv[m * 8192 + n]);
    float val = bf2f(gv[m * 8192 + 4096 + n]);
    float ge = 0.5f * g * (1.f + erff(g * 0.70710678118f));
    act[idx] = f2bf(val * ge);
}

extern "C" void kernel_launch(void* const* d_in, const int* in_sizes, int n_in,
                              void* d_out, int out_size, void* d_ws, size_t ws_size,
                              hipStream_t stream) {
    const unsigned short* x        = (const unsigned short*)d_in[0];
    const void* vs       = d_in[3];
    const void* w_qkv    = d_in[4];
    const void* w_out    = d_in[5];
    const void* w_gate   = d_in[6];
    const void* b_gate   = d_in[7];
    const void* w_mlp_g  = d_in[8];
    const void* b_mlp_g  = d_in[9];
    const void* w_mlp_o  = d_in[10];
    const void* b_mlp_o  = d_in[11];
    float* out = (float*)d_out;    // reference output dtype is float32
    char* ws = (char*)d_ws;

    if (n_in < 12) return;
    if (in_sizes[0] != 4194304 || in_sizes[3] != 2048 || in_sizes[4] != 3145728 ||
        in_sizes[8] != 8388608 || in_sizes[10] != 4194304 || in_sizes[7] != 1024) return;

    const size_t o_T   = 0;            // transposed weights, 35,651,584
    const size_t o_Qg  = 35651584;     // Qg 16 KiB + flag (32 KiB reserved)
    const size_t o_h   = 35684352;     // 8,388,608
    const size_t o_B   = 44072960;     // 25,165,824: qkv | attnb, ao, gl
    const size_t o_C   = 69238784;     // 25,165,824: q_rb,k_rb,v_rb | x1, act
    const size_t o_gv  = 94404608;     // 67,108,864
    const size_t total = 161513472;
    if (ws_size < total) return;

    unsigned short* wqkvT  = (unsigned short*)(ws + o_T);             // [3072,1024]
    unsigned short* woutT  = (unsigned short*)(ws + o_T + 6291456);   // [1024,1024]
    unsigned short* wgateT = (unsigned short*)(ws + o_T + 8388608);   // [1024,1024]
    unsigned short* wmgT   = (unsigned short*)(ws + o_T + 10485760);  // [8192,1024]
    unsigned short* wmoT   = (unsigned short*)(ws + o_T + 27262976);  // [1024,4096]
    float*          Qg     = (float*)(ws + o_Qg);
    int*            flagp  = (int*)(ws + o_Qg + 16384);
    unsigned short* h      = (unsigned short*)(ws + o_h);
    unsigned short* qkv    = (unsigned short*)(ws + o_B);
    unsigned short* attnb  = (unsigned short*)(ws + o_B);             // after qkv dead
    unsigned short* ao     = (unsigned short*)(ws + o_B + 8388608);
    unsigned short* gl     = (unsigned short*)(ws + o_B + 16777216);
    unsigned short* q_rb   = (unsigned short*)(ws + o_C);
    unsigned short* k_rb   = (unsigned short*)(ws + o_C + 8388608);
    unsigned short* v_rb   = (unsigned short*)(ws + o_C + 16777216);
    unsigned short* x1     = (unsigned short*)(ws + o_C);             // after attn done
    unsigned short* act    = (unsigned short*)(ws + o_C + 8388608);   // after attn done
    unsigned short* gv     = (unsigned short*)(ws + o_gv);

    detect_kernel<<<1, 256, 0, stream>>>(x, flagp);
    householder_kernel<<<1, 64, 0, stream>>>(vs, Qg, flagp);

    dim3 tb(32, 8);
    transpose_any<<<dim3(3072 / 32, 1024 / 32), tb, 0, stream>>>(w_qkv,   wqkvT, 1024, 3072, flagp);
    transpose_any<<<dim3(1024 / 32, 1024 / 32), tb, 0, stream>>>(w_out,   woutT, 1024, 1024, flagp);
    transpose_any<<<dim3(1024 / 32, 1024 / 32), tb, 0, stream>>>(w_gate,  wgateT, 1024, 1024, flagp);
    transpose_any<<<dim3(8192 / 32, 1024 / 32), tb, 0, stream>>>(w_mlp_g, wmgT, 1024, 8192, flagp);
    transpose_any<<<dim3(1024 / 32, 4096 / 32), tb, 0, stream>>>(w_mlp_o, wmoT, 4096, 1024, flagp);

    rmsnorm2<<<NTOK, 256, 0, stream>>>(x, h, flagp);
    gemm_bt<<<32 * 24, 256, 0, stream>>>(h, wqkvT, qkv, nullptr, nullptr, flagp, NTOK, 3072, 1024, 0);
    qk_rope2<<<NTOK * NH, 64, 0, stream>>>(qkv, Qg, q_rb, k_rb, v_rb);
    attn_mfma<<<BT * NH * (SEQ / 128), 512, 0, stream>>>(q_rb, k_rb, v_rb, attnb);
    gemm_bt<<<32 * 8, 256, 0, stream>>>(attnb, woutT, ao, nullptr, nullptr, flagp, NTOK, 1024, 1024, 0);
    gemm_bt<<<32 * 8, 256, 0, stream>>>(ao, wgateT, gl, nullptr, nullptr, flagp, NTOK, 1024, 1024, 0);
    combine_gate<<<NTOK * DIM / 256, 256, 0, stream>>>(x, ao, gl, b_gate, x1, flagp);
    rmsnorm2<<<NTOK, 256, 0, stream>>>(x1, h, nullptr);
    gemm_bt<<<32 * 64, 256, 0, stream>>>(h, wmgT, gv, b_mlp_g, nullptr, flagp, NTOK, 8192, 1024, 0);
    glu_kernel<<<NTOK * 4096 / 256, 256, 0, stream>>>(gv, act);
    gemm_bt<<<32 * 8, 256, 0, stream>>>(act, wmoT, (void*)out, b_mlp_o, x1, flagp, NTOK, 1024, 4096, 1);
}

// Round 8
// 916.601 us; speedup vs baseline: 5.6090x; 1.2327x over previous
//
#include <hip/hip_runtime.h>
#include <hip/hip_bf16.h>
#include <math.h>

#define BT 2
#define SEQ 2048
#define DIM 1024
#define NH 16
#define HD 64
#define NTOK (BT*SEQ)          // 4096

typedef __attribute__((ext_vector_type(4))) float floatx4;
typedef __attribute__((ext_vector_type(8))) short shortx8;   // 8 bf16 = 4 VGPRs (MFMA frag)
typedef __attribute__((ext_vector_type(4))) short shortx4;

__device__ __forceinline__ float bf2f(unsigned short u) {
    unsigned int x = ((unsigned int)u) << 16;
    return __builtin_bit_cast(float, x);
}
__device__ __forceinline__ unsigned short f2bf(float f) {
    unsigned int x = __builtin_bit_cast(unsigned int, f);
    unsigned int lsb = (x >> 16) & 1u;
    x += 0x7fffu + lsb;
    return (unsigned short)(x >> 16);
}
// dual-dtype input read: isbf=1 -> bf16, else fp32 (validated: inputs are fp32)
__device__ __forceinline__ float ldin_f(const void* p, size_t i, int isbf) {
    return isbf ? bf2f(((const unsigned short*)p)[i]) : ((const float*)p)[i];
}

// ---------------- input dtype detection (validated R1->R2) ----------------
__global__ void detect_kernel(const unsigned short* __restrict__ x, int* __restrict__ flag) {
    __shared__ int cnt;
    if (threadIdx.x == 0) cnt = 0;
    __syncthreads();
    unsigned short u = x[(size_t)threadIdx.x * 2];
    int e = (u >> 7) & 0xFF;
    if (e >= 100 && e <= 140) atomicAdd(&cnt, 1);
    __syncthreads();
    if (threadIdx.x == 0) *flag = (cnt >= 192) ? 1 : 0;
}

// ---------------- transpose (any float dtype -> bf16) ----------------
__global__ void transpose_any(const void* __restrict__ in,
                              unsigned short* __restrict__ out, int R, int C,
                              const int* __restrict__ flagp) {
    int isbf = *flagp;
    __shared__ unsigned short tile[32][33];
    int c0 = blockIdx.x * 32, r0 = blockIdx.y * 32;
    int tx = threadIdx.x, ty = threadIdx.y;
#pragma unroll
    for (int i = 0; i < 4; i++) {
        size_t idx = (size_t)(r0 + ty + i * 8) * C + c0 + tx;
        tile[ty + i * 8][tx] = isbf ? ((const unsigned short*)in)[idx]
                                    : f2bf(((const float*)in)[idx]);
    }
    __syncthreads();
#pragma unroll
    for (int i = 0; i < 4; i++)
        out[(size_t)(c0 + ty + i * 8) * R + r0 + tx] = tile[tx][ty + i * 8];
}

// ---------------- Householder Q (64x64 fp32), register-resident columns ----------
// Thread j owns column Q[:,j] in 64 VGPRs. v staged in LDS (broadcast reads),
// preloaded to registers; reductions use split accumulators (no LDS dep chain).
__global__ __launch_bounds__(64) void householder_kernel(const void* __restrict__ vs,
                                                         float* __restrict__ Qg,
                                                         const int* __restrict__ flagp) {
    int isbf = *flagp;
    __shared__ float vsh[64];
    int j = threadIdx.x;
    float Qc[64];
#pragma unroll
    for (int i = 0; i < 64; i++) Qc[i] = (i == j) ? 1.f : 0.f;
    for (int r = 0; r < 32; r++) {
        vsh[j] = ldin_f(vs, r * 64 + j, isbf);
        __syncthreads();
        float va[64];
#pragma unroll
        for (int i = 0; i < 64; i++) va[i] = vsh[i];
        float vn0 = 0.f, vn1 = 0.f, vn2 = 0.f, vn3 = 0.f;
        float t0 = 0.f, t1 = 0.f, t2 = 0.f, t3 = 0.f;
#pragma unroll
        for (int i = 0; i < 16; i++) {
            vn0 += va[4 * i + 0] * va[4 * i + 0];
            vn1 += va[4 * i + 1] * va[4 * i + 1];
            vn2 += va[4 * i + 2] * va[4 * i + 2];
            vn3 += va[4 * i + 3] * va[4 * i + 3];
            t0 += va[4 * i + 0] * Qc[4 * i + 0];
            t1 += va[4 * i + 1] * Qc[4 * i + 1];
            t2 += va[4 * i + 2] * Qc[4 * i + 2];
            t3 += va[4 * i + 3] * Qc[4 * i + 3];
        }
        float vn = (vn0 + vn1) + (vn2 + vn3) + 1e-8f;
        float t = (t0 + t1) + (t2 + t3);
        float c = (2.f / vn) * t;
#pragma unroll
        for (int i = 0; i < 64; i++) Qc[i] -= c * va[i];
        __syncthreads();
    }
#pragma unroll
    for (int i = 0; i < 64; i++) Qg[i * 64 + j] = Qc[i];
}

// ---------------- rmsnorm over D=1024, LDS tree reduction ----------------
__global__ __launch_bounds__(256) void rmsnorm2(const void* __restrict__ x,
                                                unsigned short* __restrict__ h,
                                                const int* __restrict__ flagp) {
    int isbf = flagp ? *flagp : 1;
    __shared__ float red[256];
    int row = blockIdx.x, t = threadIdx.x;
    size_t base = (size_t)row * DIM;
    float v[4];
    float ss = 0.f;
#pragma unroll
    for (int i = 0; i < 4; i++) {
        v[i] = ldin_f(x, base + t + 256 * i, isbf);
        ss += v[i] * v[i];
    }
    red[t] = ss;
    __syncthreads();
    for (int s = 128; s > 0; s >>= 1) {
        if (t < s) red[t] += red[t + s];
        __syncthreads();
    }
    float rs = rsqrtf(red[0] * (1.f / 1024.f) + 1e-6f);
#pragma unroll
    for (int i = 0; i < 4; i++) h[base + t + 256 * i] = f2bf(v[i] * rs);
}

// ---------------- MFMA GEMM: C[M,N] = A[M,K] * Bt[N,K]^T (+bias +resid) --------------
#define GBM 128
#define GBN 128
#define GBK 32
#define ASTR 40

__global__ __launch_bounds__(256) void gemm_bt(const unsigned short* __restrict__ A,
                                               const unsigned short* __restrict__ Bt,
                                               void* __restrict__ C,
                                               const void* __restrict__ bias,
                                               const unsigned short* __restrict__ resid,
                                               const int* __restrict__ flagp,
                                               int M, int N, int K, int c_f32) {
    __shared__ unsigned short As[GBM][ASTR];
    __shared__ unsigned short Bs[GBN][ASTR];
    int bisbf = (bias && flagp) ? *flagp : 1;
    int nbn = N / GBN;
    int m0 = (blockIdx.x / nbn) * GBM;
    int n0 = (blockIdx.x % nbn) * GBN;
    int t = threadIdx.x;
    int lane = t & 63;
    int w = t >> 6;
    int wr = (w >> 1) * 64;
    int wc = (w & 1) * 64;
    int lr = lane & 15;
    int kg = lane >> 4;

    floatx4 acc[4][4];
#pragma unroll
    for (int i = 0; i < 4; i++)
#pragma unroll
        for (int j = 0; j < 4; j++) acc[i][j] = (floatx4){0.f, 0.f, 0.f, 0.f};

    int srow = t >> 1;
    int skseg = (t & 1) * 16;
    const unsigned short* Aptr = A + (size_t)(m0 + srow) * K + skseg;
    const unsigned short* Bptr = Bt + (size_t)(n0 + srow) * K + skseg;

    for (int k0 = 0; k0 < K; k0 += GBK) {
        shortx8 a0 = *(const shortx8*)(Aptr + k0);
        shortx8 a1 = *(const shortx8*)(Aptr + k0 + 8);
        shortx8 b0 = *(const shortx8*)(Bptr + k0);
        shortx8 b1 = *(const shortx8*)(Bptr + k0 + 8);
        __syncthreads();
        *(shortx8*)&As[srow][skseg] = a0;
        *(shortx8*)&As[srow][skseg + 8] = a1;
        *(shortx8*)&Bs[srow][skseg] = b0;
        *(shortx8*)&Bs[srow][skseg + 8] = b1;
        __syncthreads();
        shortx8 af[4], bfv[4];
#pragma unroll
        for (int i = 0; i < 4; i++) af[i] = *(const shortx8*)&As[wr + i * 16 + lr][kg * 8];
#pragma unroll
        for (int j = 0; j < 4; j++) bfv[j] = *(const shortx8*)&Bs[wc + j * 16 + lr][kg * 8];
#pragma unroll
        for (int i = 0; i < 4; i++)
#pragma unroll
            for (int j = 0; j < 4; j++)
                acc[i][j] = __builtin_amdgcn_mfma_f32_16x16x32_bf16(af[i], bfv[j], acc[i][j], 0, 0, 0);
    }
#pragma unroll
    for (int i = 0; i < 4; i++) {
#pragma unroll
        for (int j = 0; j < 4; j++) {
            int col = n0 + wc + j * 16 + lr;
            int rbase = m0 + wr + i * 16 + kg * 4;
            float bv = bias ? ldin_f(bias, col, bisbf) : 0.f;
#pragma unroll
            for (int r = 0; r < 4; r++) {
                float val = acc[i][j][r] + bv;
                size_t oidx = (size_t)(rbase + r) * N + col;
                if (resid) val += bf2f(resid[oidx]);
                if (c_f32) ((float*)C)[oidx] = val;
                else       ((unsigned short*)C)[oidx] = f2bf(val);
            }
        }
    }
}

// ---------------- Householder^-1 + RoPE + Householder (R6-validated) ------------
__global__ __launch_bounds__(64) void qk_rope2(const unsigned short* __restrict__ qkv,
                                               const float* __restrict__ Qg,
                                               unsigned short* __restrict__ q_r,
                                               unsigned short* __restrict__ k_r,
                                               unsigned short* __restrict__ v_r) {
    int blk = blockIdx.x;            // = ts*16 + h
    int h = blk & 15;
    int ts = blk >> 4;               // b*SEQ + s
    int s = ts & 2047;
    int b = ts >> 11;
    int d = threadIdx.x;             // 0..63
    __shared__ float qs[64], ks[64], q1s[64], k1s[64];
    const unsigned short* base = qkv + (size_t)ts * 3072 + h * 64;
    qs[d] = bf2f(base[d]);
    ks[d] = bf2f(base[1024 + d]);
    unsigned short vv = base[2048 + d];
    __syncthreads();
    const float* Qrow = Qg + d * 64;
    float q1 = 0.f, k1 = 0.f;
    for (int j = 0; j < 64; j++) { q1 += Qrow[j] * qs[j]; k1 += Qrow[j] * ks[j]; }
    q1s[d] = q1; k1s[d] = k1;
    __syncthreads();
    int fi = d & 31;
    float invf = powf(10000.f, -(float)fi / 32.f);
    float ang = (float)s * invf;
    float cv = cosf(ang), sv = sinf(ang);
    float rq = (d < 32) ? -q1s[d + 32] : q1s[d - 32];
    float rk = (d < 32) ? -k1s[d + 32] : k1s[d - 32];
    float q2 = q1 * cv + rq * sv;
    float k2 = k1 * cv + rk * sv;
    __syncthreads();
    q1s[d] = q2; k1s[d] = k2;
    __syncthreads();
    float q3 = 0.f, k3 = 0.f;
    for (int j = 0; j < 64; j++) {
        float Qjd = Qg[j * 64 + d];
        q3 += Qjd * q1s[j];
        k3 += Qjd * k1s[j];
    }
    size_t bh_off = ((size_t)(b * NH + h) * SEQ + s) * HD;
    q_r[bh_off + d] = f2bf(q3);
    k_r[bh_off + d] = f2bf(k3);
    v_r[bh_off + d] = vv;
}

// ---------------- MFMA flash attention (block-causal), R7-validated -----------------
__global__ __launch_bounds__(512) void attn_mfma(const unsigned short* __restrict__ q_r,
                                                 const unsigned short* __restrict__ k_r,
                                                 const unsigned short* __restrict__ v_r,
                                                 unsigned short* __restrict__ attn) {
    __shared__ unsigned short Ks[32][72];        // K-tile [key][dim]
    __shared__ unsigned short Vt[64][40];        // V^T tile [dim][key]
    __shared__ unsigned short Ps[8][16][40];     // per-wave P round-trip [row][key]
    int bid = blockIdx.x;
    int qblk = 15 - (bid & 15);                  // big q-blocks first
    int bh = bid >> 4;
    int b = bh >> 4, h = bh & 15;
    size_t bh_off = (size_t)bh * SEQ * HD;
    int tid = threadIdx.x;
    int wv = tid >> 6, lane = tid & 63;
    int l16 = lane & 15, quad = lane >> 4;
    int q0 = qblk * 128 + wv * 16;

    const unsigned short* qrow = q_r + bh_off + (size_t)(q0 + l16) * HD + quad * 8;
    shortx8 aq0 = *(const shortx8*)(qrow);
    shortx8 aq1 = *(const shortx8*)(qrow + 32);

    floatx4 o[4];
#pragma unroll
    for (int nt = 0; nt < 4; nt++) o[nt] = (floatx4){0.f, 0.f, 0.f, 0.f};
    float m4[4] = {-1e30f, -1e30f, -1e30f, -1e30f};
    float l4[4] = {0.f, 0.f, 0.f, 0.f};

    int nk = (qblk + 1) * 128;
    int srow = tid >> 4;              // 0..31 (staging)
    int scol = (tid & 15) * 4;        // 0..60
    const unsigned short* kbase = k_r + bh_off + (size_t)srow * HD + scol;
    const unsigned short* vbase = v_r + bh_off + (size_t)srow * HD + scol;

    for (int k0 = 0; k0 < nk; k0 += 32) {
        __syncthreads();
        shortx4 kv4 = *(const shortx4*)(kbase + (size_t)k0 * HD);
        shortx4 vv4 = *(const shortx4*)(vbase + (size_t)k0 * HD);
        *(shortx4*)&Ks[srow][scol] = kv4;
        Vt[scol + 0][srow] = vv4[0];
        Vt[scol + 1][srow] = vv4[1];
        Vt[scol + 2][srow] = vv4[2];
        Vt[scol + 3][srow] = vv4[3];
        __syncthreads();

        floatx4 sc[2];
#pragma unroll
        for (int t = 0; t < 2; t++) {
            shortx8 bk0 = *(const shortx8*)&Ks[t * 16 + l16][quad * 8];
            shortx8 bk1 = *(const shortx8*)&Ks[t * 16 + l16][32 + quad * 8];
            floatx4 z = (floatx4){0.f, 0.f, 0.f, 0.f};
            z = __builtin_amdgcn_mfma_f32_16x16x32_bf16(aq0, bk0, z, 0, 0, 0);
            z = __builtin_amdgcn_mfma_f32_16x16x32_bf16(aq1, bk1, z, 0, 0, 0);
            sc[t] = z;
        }
#pragma unroll
        for (int r = 0; r < 4; r++) {
            float s0 = sc[0][r] * 0.125f;
            float s1 = sc[1][r] * 0.125f;
            float mt = fmaxf(s0, s1);
#pragma unroll
            for (int msk = 1; msk < 16; msk <<= 1) mt = fmaxf(mt, __shfl_xor(mt, msk, 64));
            float nmr = fmaxf(m4[r], mt);
            float al = __expf(m4[r] - nmr);
            m4[r] = nmr;
            float p0 = __expf(s0 - nmr);
            float p1 = __expf(s1 - nmr);
            float ps = p0 + p1;
#pragma unroll
            for (int msk = 1; msk < 16; msk <<= 1) ps += __shfl_xor(ps, msk, 64);
            l4[r] = l4[r] * al + ps;
#pragma unroll
            for (int nt = 0; nt < 4; nt++) o[nt][r] *= al;
            Ps[wv][quad * 4 + r][l16] = f2bf(p0);
            Ps[wv][quad * 4 + r][16 + l16] = f2bf(p1);
        }
        __syncthreads();

        shortx8 ap = *(const shortx8*)&Ps[wv][l16][quad * 8];
#pragma unroll
        for (int nt = 0; nt < 4; nt++) {
            shortx8 bv = *(const shortx8*)&Vt[nt * 16 + l16][quad * 8];
            o[nt] = __builtin_amdgcn_mfma_f32_16x16x32_bf16(ap, bv, o[nt], 0, 0, 0);
        }
    }
#pragma unroll
    for (int r = 0; r < 4; r++) {
        float inv_l = 1.f / l4[r];
        int s = q0 + quad * 4 + r;
        unsigned short* op = attn + ((size_t)(b * SEQ + s)) * DIM + h * 64;
#pragma unroll
        for (int nt = 0; nt < 4; nt++) op[nt * 16 + l16] = f2bf(o[nt][r] * inv_l);
    }
}

// ---------------- gated residual combine: x1 = x + ao*sigmoid(gl + bg) ----------------
__global__ void combine_gate(const void* __restrict__ x,
                             const unsigned short* __restrict__ ao,
                             const unsigned short* __restrict__ gl,
                             const void* __restrict__ bg,
                             unsigned short* __restrict__ x1,
                             const int* __restrict__ flagp) {
    int isbf = *flagp;
    size_t idx = (size_t)blockIdx.x * 256 + threadIdx.x;
    float a = bf2f(ao[idx]);
    float z = bf2f(gl[idx]) + ldin_f(bg, idx & 1023, isbf);
    float sg = 1.f / (1.f + __expf(-z));
    x1[idx] = f2bf(ldin_f(x, idx, isbf) + a * sg);
}

// ---------------- GLU with exact GELU ----------------
__global__ void glu_kernel(const unsigned short* __restrict__ gv,
                           unsigned short* __restrict__ act) {
    size_t idx = (size_t)blockIdx.x * 256 + threadIdx.x;     // over 4096*4096
    size_t m = idx >> 12, n = idx & 4095;
    float g = bf2f(gv[m * 8192 + n]);
    float val = bf2f(gv[m * 8192 + 4096 + n]);
    float ge = 0.5f * g * (1.f + erff(g * 0.70710678118f));
    act[idx] = f2bf(val * ge);
}

extern "C" void kernel_launch(void* const* d_in, const int* in_sizes, int n_in,
                              void* d_out, int out_size, void* d_ws, size_t ws_size,
                              hipStream_t stream) {
    const unsigned short* x        = (const unsigned short*)d_in[0];
    const void* vs       = d_in[3];
    const void* w_qkv    = d_in[4];
    const void* w_out    = d_in[5];
    const void* w_gate   = d_in[6];
    const void* b_gate   = d_in[7];
    const void* w_mlp_g  = d_in[8];
    const void* b_mlp_g  = d_in[9];
    const void* w_mlp_o  = d_in[10];
    const void* b_mlp_o  = d_in[11];
    float* out = (float*)d_out;    // reference output dtype is float32
    char* ws = (char*)d_ws;

    if (n_in < 12) return;
    if (in_sizes[0] != 4194304 || in_sizes[3] != 2048 || in_sizes[4] != 3145728 ||
        in_sizes[8] != 8388608 || in_sizes[10] != 4194304 || in_sizes[7] != 1024) return;

    const size_t o_T   = 0;            // transposed weights, 35,651,584
    const size_t o_Qg  = 35651584;     // Qg 16 KiB + flag (32 KiB reserved)
    const size_t o_h   = 35684352;     // 8,388,608
    const size_t o_B   = 44072960;     // 25,165,824: qkv | attnb, ao, gl
    const size_t o_C   = 69238784;     // 25,165,824: q_rb,k_rb,v_rb | x1, act
    const size_t o_gv  = 94404608;     // 67,108,864
    const size_t total = 161513472;
    if (ws_size < total) return;

    unsigned short* wqkvT  = (unsigned short*)(ws + o_T);             // [3072,1024]
    unsigned short* woutT  = (unsigned short*)(ws + o_T + 6291456);   // [1024,1024]
    unsigned short* wgateT = (unsigned short*)(ws + o_T + 8388608);   // [1024,1024]
    unsigned short* wmgT   = (unsigned short*)(ws + o_T + 10485760);  // [8192,1024]
    unsigned short* wmoT   = (unsigned short*)(ws + o_T + 27262976);  // [1024,4096]
    float*          Qg     = (float*)(ws + o_Qg);
    int*            flagp  = (int*)(ws + o_Qg + 16384);
    unsigned short* h      = (unsigned short*)(ws + o_h);
    unsigned short* qkv    = (unsigned short*)(ws + o_B);
    unsigned short* attnb  = (unsigned short*)(ws + o_B);             // after qkv dead
    unsigned short* ao     = (unsigned short*)(ws + o_B + 8388608);
    unsigned short* gl     = (unsigned short*)(ws + o_B + 16777216);
    unsigned short* q_rb   = (unsigned short*)(ws + o_C);
    unsigned short* k_rb   = (unsigned short*)(ws + o_C + 8388608);
    unsigned short* v_rb   = (unsigned short*)(ws + o_C + 16777216);
    unsigned short* x1     = (unsigned short*)(ws + o_C);             // after attn done
    unsigned short* act    = (unsigned short*)(ws + o_C + 8388608);   // after attn done
    unsigned short* gv     = (unsigned short*)(ws + o_gv);

    detect_kernel<<<1, 256, 0, stream>>>(x, flagp);
    householder_kernel<<<1, 64, 0, stream>>>(vs, Qg, flagp);

    dim3 tb(32, 8);
    transpose_any<<<dim3(3072 / 32, 1024 / 32), tb, 0, stream>>>(w_qkv,   wqkvT, 1024, 3072, flagp);
    transpose_any<<<dim3(1024 / 32, 1024 / 32), tb, 0, stream>>>(w_out,   woutT, 1024, 1024, flagp);
    transpose_any<<<dim3(1024 / 32, 1024 / 32), tb, 0, stream>>>(w_gate,  wgateT, 1024, 1024, flagp);
    transpose_any<<<dim3(8192 / 32, 1024 / 32), tb, 0, stream>>>(w_mlp_g, wmgT, 1024, 8192, flagp);
    transpose_any<<<dim3(1024 / 32, 4096 / 32), tb, 0, stream>>>(w_mlp_o, wmoT, 4096, 1024, flagp);

    rmsnorm2<<<NTOK, 256, 0, stream>>>(x, h, flagp);
    gemm_bt<<<32 * 24, 256, 0, stream>>>(h, wqkvT, qkv, nullptr, nullptr, flagp, NTOK, 3072, 1024, 0);
    qk_rope2<<<NTOK * NH, 64, 0, stream>>>(qkv, Qg, q_rb, k_rb, v_rb);
    attn_mfma<<<BT * NH * (SEQ / 128), 512, 0, stream>>>(q_rb, k_rb, v_rb, attnb);
    gemm_bt<<<32 * 8, 256, 0, stream>>>(attnb, woutT, ao, nullptr, nullptr, flagp, NTOK, 1024, 1024, 0);
    gemm_bt<<<32 * 8, 256, 0, stream>>>(ao, wgateT, gl, nullptr, nullptr, flagp, NTOK, 1024, 1024, 0);
    combine_gate<<<NTOK * DIM / 256, 256, 0, stream>>>(x, ao, gl, b_gate, x1, flagp);
    rmsnorm2<<<NTOK, 256, 0, stream>>>(x1, h, nullptr);
    gemm_bt<<<32 * 64, 256, 0, stream>>>(h, wmgT, gv, b_mlp_g, nullptr, flagp, NTOK, 8192, 1024, 0);
    glu_kernel<<<NTOK * 4096 / 256, 256, 0, stream>>>(gv, act);
    gemm_bt<<<32 * 8, 256, 0, stream>>>(act, wmoT, (void*)out, b_mlp_o, x1, flagp, NTOK, 1024, 4096, 1);
}